// Round 14
// baseline (77.139 us; speedup 1.0000x reference)
//
#include <hip/hip_runtime.h>

typedef float f32x4 __attribute__((ext_vector_type(4)));
typedef short bf16x8 __attribute__((ext_vector_type(8)));

// LDS map (bytes):
//   [0, 29696)      per-wave x-stage: 4 waves x 16 rows x 464B (224 bf16 + pad)
//                   (setup reuses [0,7232) to stage raw W1/W2 for compose)
//   [29696, 37120)  W12 bf16 (setup only; preloaded to regs, then DEAD)
//   [29696, 38912)  per-wave y (ALIASES W12 after preload): 4 x 16 x 144B
//   [38912, 38976)  b12 (16 f32)
// Total 38976 B -> 4 blocks/CU (155.9 KB of 160 KB).
#define XS 464
#define WOFF 29696
#define YOFF 29696
#define YS 144
#define BOFF 38912

// RNE float->bf16, integer path (setup only — cold).
__device__ __forceinline__ unsigned short f2bf(float f) {
  unsigned u = __builtin_bit_cast(unsigned, f);
  u += 0x7FFFu + ((u >> 16) & 1u);
  return (unsigned short)(u >> 16);
}
// HOT path: single-instruction packed RNE convert (a->low16, b->high16).
__device__ __forceinline__ unsigned packbf2(float a, float b) {
  unsigned r;
  asm("v_cvt_pk_bf16_f32 %0, %1, %2" : "=v"(r) : "v"(a), "v"(b));
  return r;
}
// Maximal streaming-read policy: no-allocate at L1/L2/LLC (sc0 sc1 nt).
// Compiler does NOT track these loads -> consumer side needs explicit
// s_waitcnt vmcnt(0) + sched_barrier(0) (rule #18).
__device__ __forceinline__ f32x4 ldstream(const void* p) {
  f32x4 r;
  asm volatile("global_load_dwordx4 %0, %1, off sc0 sc1 nt"
               : "=v"(r) : "v"(p) : "memory");
  return r;
}

__global__ __launch_bounds__(256, 2) void mnist_mfma(
    const float* __restrict__ x, const float* __restrict__ W1,
    const float* __restrict__ b1, const float* __restrict__ W2,
    const float* __restrict__ b2, const float* __restrict__ W3,
    const float* __restrict__ b3, float* __restrict__ out, int nimg)
{
  __shared__ __align__(16) char smem[38976];
  float* smemF = (float*)smem;
  const int tid = threadIdx.x;
  const int lane = tid & 63;
  const int waveid = tid >> 6;

  // ---- setup: stage raw W1/W2, compose W12 = W1∘W2 (bf16) + b12 ----------
  for (int i = tid; i < 784; i += 256) smemF[i] = W1[i];
  for (int i = tid; i < 1024; i += 256) smemF[784 + i] = W2[i];
  __syncthreads();

  unsigned short* w12b = (unsigned short*)(smem + WOFF);
  for (int e = tid; e < 3136; e += 256) {
    int f2 = e / 196, k = e - f2 * 196;
    int r14 = k / 14, c14 = k - r14 * 14;
    int pp = (r14 % 7) * 7 + (c14 % 7);          // within-patch pixel
    int q = (r14 / 7) * 2 + (c14 / 7);           // patch block i2*2+j2
    float s = 0.f;
#pragma unroll
    for (int f = 0; f < 16; ++f)
      s = fmaf(smemF[f * 49 + pp], smemF[784 + f2 * 64 + q * 16 + f], s);
    w12b[f2 * 232 + k] = f2bf(s);
  }
  for (int e = tid; e < 576; e += 256) {         // zero K-pad [196,232)
    int f2 = e / 36;
    w12b[f2 * 232 + 196 + (e - f2 * 36)] = 0;
  }
  if (tid < 16) {                                // b12 = b2 + b1-through-W2
    float s = b2[tid];
#pragma unroll
    for (int k = 0; k < 64; ++k)
      s = fmaf(b1[k & 15], smemF[784 + tid * 64 + k], s);
    smemF[BOFF / 4 + tid] = s;
  }
  __syncthreads();

  // ---- preload fragments into registers ----------------------------------
  bf16x8 wfrag[7];                               // W12 B-frags (28 VGPRs)
#pragma unroll
  for (int i = 0; i < 7; ++i)
    wfrag[i] = *(const bf16x8*)(smem + WOFF + (lane & 15) * XS + (lane >> 4) * 16 + i * 64);

  bf16x8 w3f[2];                                 // W3 A-frags (rows>=10 zero)
  {
    int o = lane & 15, kb = (lane >> 4) * 8;
#pragma unroll
    for (int mi = 0; mi < 2; ++mi) {
      float v[8];
#pragma unroll
      for (int j = 0; j < 8; ++j)
        v[j] = (o < 10) ? W3[o * 64 + kb + 32 * mi + j] : 0.f;
      unsigned t[4];
      t[0] = packbf2(v[0], v[1]); t[1] = packbf2(v[2], v[3]);
      t[2] = packbf2(v[4], v[5]); t[3] = packbf2(v[6], v[7]);
      w3f[mi] = __builtin_bit_cast(bf16x8, *(unsigned(*)[4])t);
    }
  }
  const float b12v = smemF[BOFF / 4 + (lane & 15)];
  float b3v[4];
#pragma unroll
  for (int r = 0; r < 4; ++r) {
    int o = (lane >> 4) * 4 + r;
    b3v[r] = (o < 10) ? b3[o] : 0.f;
  }
  // All waves have W12 in registers; y-region may now alias it.
  __syncthreads();

  // ---- per-wave zero of x-stage K-pad (bytes [392,464) of each row) ------
  char* xw = smem + waveid * 7424;
#pragma unroll
  for (int j = 0; j < 5; ++j) {
    int idx = lane + 64 * j;
    if (idx < 288) {
      int row = idx / 18, d = idx - row * 18;
      *(unsigned*)(xw + row * XS + 392 + d * 4) = 0;
    }
  }

  // ---- staging addresses: raster float4 -> quadrant-stream bf16 pairs ----
  unsigned wa0[13]; unsigned strm = 0;
#pragma unroll
  for (int it = 0; it < 13; ++it) {
    int gi = lane + 64 * it;
    int im = gi / 196, rem = gi - im * 196;      // image, float4 within image
    int rr = rem / 7, t = rem - rr * 7;          // pixel row, 4-px group
    int c2 = 2 * t;                              // first bf16-pair column
    int J = c2 / 7, cq = c2 - 7 * J;
    int row = im * 4 + (rr / 14) * 2 + J;        // M-row = im*4 + (I*2+J)
    int kp = (rr % 14) * 7 + cq;                 // pair index in quadrant
    wa0[it] = waveid * 7424 + row * XS + kp * 4;
    if (t == 3) strm |= (1u << it);              // second pair crosses J-half
  }

  const unsigned xrd = waveid * 7424 + (lane & 15) * XS + (lane >> 4) * 16;
  const unsigned ywb = YOFF + waveid * 2304 + (lane & 15) * 2;
  const unsigned yrd = YOFF + waveid * 2304 + (lane & 15) * YS + (lane >> 4) * 16;

  const int NU = nimg >> 4;                      // 16-image units
  const int WST = (int)(gridDim.x << 2);         // total waves
  const int w0 = (int)(blockIdx.x << 2) + waveid;
  const int ng4 = nimg >> 2;                     // 4-image groups

  f32x4 cur[13];
  const f32x4* __restrict__ xq0 = (const f32x4*)x;
  auto issue4 = [&](int g4) {                    // 13 coalesced streaming loads
    const f32x4* p = xq0 + (size_t)g4 * 784;
#pragma unroll
    for (int it = 0; it < 12; ++it)
      cur[it] = ldstream(p + lane + 64 * it);
    if (lane < 16) cur[12] = ldstream(p + 768 + lane);
  };

  if (w0 < NU) issue4(w0 * 4);

  for (int u = w0; u < NU; u += WST) {
#pragma unroll 1
    for (int sb = 0; sb < 4; ++sb) {
      // asm loads are untracked: explicit drain + scheduling fence before use
      asm volatile("s_waitcnt vmcnt(0)" ::: "memory");
      __builtin_amdgcn_sched_barrier(0);
      // stage cur -> LDS: 26 x v_cvt_pk_bf16_f32 + 26 x ds_write_b32
#pragma unroll
      for (int it = 0; it < 13; ++it) {
        if (it == 12 && lane >= 16) continue;
        f32x4 v = cur[it];
        unsigned a0 = wa0[it];
        unsigned d = ((strm >> it) & 1) ? 440u : 4u;
        *(unsigned*)(smem + a0) = packbf2(v.x, v.y);
        *(unsigned*)(smem + a0 + d) = packbf2(v.z, v.w);
      }
      // prefetch next 4-image group (1 sub-batch deep)
      int ng = (sb < 3) ? (u * 4 + sb + 1) : ((u + WST) * 4);
      if (ng < ng4) issue4(ng);
      // GEMM1: y(16 rows x 16 f2) = P(16 x 224) * W12(224 x 16)
      f32x4 acc = {0.f, 0.f, 0.f, 0.f};
#pragma unroll
      for (int i = 0; i < 7; ++i) {
        bf16x8 a = *(const bf16x8*)(smem + xrd + 64 * i);
        acc = __builtin_amdgcn_mfma_f32_16x16x32_bf16(a, wfrag[i], acc, 0, 0, 0);
      }
      // bias + ReLU + packed bf16 convert -> y LDS
      unsigned yb = ywb + (unsigned)(sb * 4 + (lane >> 4)) * YS;
      float y0 = fmaxf(acc[0] + b12v, 0.f), y1 = fmaxf(acc[1] + b12v, 0.f);
      float y2 = fmaxf(acc[2] + b12v, 0.f), y3 = fmaxf(acc[3] + b12v, 0.f);
      unsigned p01 = packbf2(y0, y1), p23 = packbf2(y2, y3);
      *(unsigned short*)(smem + yb)      = (unsigned short)p01;
      *(unsigned short*)(smem + yb + 32) = (unsigned short)(p01 >> 16);
      *(unsigned short*)(smem + yb + 64) = (unsigned short)p23;
      *(unsigned short*)(smem + yb + 96) = (unsigned short)(p23 >> 16);
    }
    // GEMM2: z^T(16 o x 16 img) = W3(16x64) * y^T(64x16) over the unit
    f32x4 z4 = {0.f, 0.f, 0.f, 0.f};
#pragma unroll
    for (int mi = 0; mi < 2; ++mi) {
      bf16x8 bfr = *(const bf16x8*)(smem + yrd + 64 * mi);
      z4 = __builtin_amdgcn_mfma_f32_16x16x32_bf16(w3f[mi], bfr, z4, 0, 0, 0);
    }
    // log_softmax over o = (lane>>4)*4 + r (10 valid), img = lane&15
    float zv[4], mval = -3.0e38f;
#pragma unroll
    for (int r = 0; r < 4; ++r) {
      zv[r] = z4[r] + b3v[r];
      bool valid = ((lane >> 4) * 4 + r) < 10;
      mval = fmaxf(mval, valid ? zv[r] : -3.0e38f);
    }
    mval = fmaxf(mval, __shfl_xor(mval, 16, 64));
    mval = fmaxf(mval, __shfl_xor(mval, 32, 64));
    float ssum = 0.f;
#pragma unroll
    for (int r = 0; r < 4; ++r) {
      bool valid = ((lane >> 4) * 4 + r) < 10;
      ssum += valid ? __expf(zv[r] - mval) : 0.f;
    }
    ssum += __shfl_xor(ssum, 16, 64);
    ssum += __shfl_xor(ssum, 32, 64);
    const float lse = mval + __logf(ssum);
    float* op = out + (size_t)(u * 16 + (lane & 15)) * 10;
#pragma unroll
    for (int r = 0; r < 4; ++r) {
      int o = (lane >> 4) * 4 + r;
      if (o < 10) op[o] = zv[r] - lse;
    }
  }
}

extern "C" void kernel_launch(void* const* d_in, const int* in_sizes, int n_in,
                              void* d_out, int out_size, void* d_ws, size_t ws_size,
                              hipStream_t stream) {
  const float* x  = (const float*)d_in[0];
  const float* W1 = (const float*)d_in[1];
  const float* b1 = (const float*)d_in[2];
  const float* W2 = (const float*)d_in[3];
  const float* b2 = (const float*)d_in[4];
  const float* W3 = (const float*)d_in[5];
  const float* b3 = (const float*)d_in[6];
  float* out = (float*)d_out;

  const int nimg = in_sizes[0] / 784;  // 131072
  // 1024 blocks = 4096 waves -> exactly 2 units/wave; 4 blocks/CU.
  // r10 engine + maximal streaming-read policy (sc0 sc1 nt).
  mnist_mfma<<<1024, 256, 0, stream>>>(x, W1, b1, W2, b2, W3, b3, out, nimg);
}

// Round 15
// 75.141 us; speedup vs baseline: 1.0266x; 1.0266x over previous
//
#include <hip/hip_runtime.h>

typedef float f32x4 __attribute__((ext_vector_type(4)));
typedef short bf16x8 __attribute__((ext_vector_type(8)));

// LDS map (bytes):
//   [0, 29696)      per-wave x-stage: 4 waves x 16 rows x 464B (224 bf16 + pad)
//                   (setup reuses [0,7232) to stage raw W1/W2 for compose)
//   [29696, 37120)  W12 bf16 (setup only; preloaded to regs, then DEAD)
//   [29696, 38912)  per-wave y (ALIASES W12 after preload): 4 x 16 x 144B
//   [38912, 38976)  b12 (16 f32)
// Total 38976 B -> 4 blocks/CU (155.9 KB of 160 KB).
//
// FINAL (r15 = r10 verbatim, best measured 75.1 us = 5.5 TB/s effective read):
//  - fused W1*W2 -> W12 (16x224) per-block compose, MFMA 16x16x32 GEMM1,
//    GEMM2 via W3 A-frags; waves independent after setup (no main-loop barriers)
//  - NT loads on the zero-reuse x stream: the single biggest lever (+13%)
//  - interleaved unit->wave mapping (beats blocked-contiguous under NT)
//  - falsified levers (each single-variable, in-regime): occupancy, DMA/reg
//    prefetch depth, prologue split, DRAM locality, stage-VALU, sc0/sc1 bits
#define XS 464
#define WOFF 29696
#define YOFF 29696
#define YS 144
#define BOFF 38912

// RNE float->bf16 on plain integer types.
__device__ __forceinline__ unsigned short f2bf(float f) {
  unsigned u = __builtin_bit_cast(unsigned, f);
  u += 0x7FFFu + ((u >> 16) & 1u);
  return (unsigned short)(u >> 16);
}
__device__ __forceinline__ unsigned packbf2(float a, float b) {
  return (unsigned)f2bf(a) | ((unsigned)f2bf(b) << 16);
}

__global__ __launch_bounds__(256, 2) void mnist_mfma(
    const float* __restrict__ x, const float* __restrict__ W1,
    const float* __restrict__ b1, const float* __restrict__ W2,
    const float* __restrict__ b2, const float* __restrict__ W3,
    const float* __restrict__ b3, float* __restrict__ out, int nimg)
{
  __shared__ __align__(16) char smem[38976];
  float* smemF = (float*)smem;
  const int tid = threadIdx.x;
  const int lane = tid & 63;
  const int waveid = tid >> 6;

  // ---- setup: stage raw W1/W2, compose W12 = W1∘W2 (bf16) + b12 ----------
  for (int i = tid; i < 784; i += 256) smemF[i] = W1[i];
  for (int i = tid; i < 1024; i += 256) smemF[784 + i] = W2[i];
  __syncthreads();

  unsigned short* w12b = (unsigned short*)(smem + WOFF);
  for (int e = tid; e < 3136; e += 256) {
    int f2 = e / 196, k = e - f2 * 196;
    int r14 = k / 14, c14 = k - r14 * 14;
    int pp = (r14 % 7) * 7 + (c14 % 7);          // within-patch pixel
    int q = (r14 / 7) * 2 + (c14 / 7);           // patch block i2*2+j2
    float s = 0.f;
#pragma unroll
    for (int f = 0; f < 16; ++f)
      s = fmaf(smemF[f * 49 + pp], smemF[784 + f2 * 64 + q * 16 + f], s);
    w12b[f2 * 232 + k] = f2bf(s);
  }
  for (int e = tid; e < 576; e += 256) {         // zero K-pad [196,232)
    int f2 = e / 36;
    w12b[f2 * 232 + 196 + (e - f2 * 36)] = 0;
  }
  if (tid < 16) {                                // b12 = b2 + b1-through-W2
    float s = b2[tid];
#pragma unroll
    for (int k = 0; k < 64; ++k)
      s = fmaf(b1[k & 15], smemF[784 + tid * 64 + k], s);
    smemF[BOFF / 4 + tid] = s;
  }
  __syncthreads();

  // ---- preload fragments into registers ----------------------------------
  bf16x8 wfrag[7];                               // W12 B-frags (28 VGPRs)
#pragma unroll
  for (int i = 0; i < 7; ++i)
    wfrag[i] = *(const bf16x8*)(smem + WOFF + (lane & 15) * XS + (lane >> 4) * 16 + i * 64);

  bf16x8 w3f[2];                                 // W3 A-frags (rows>=10 zero)
  {
    int o = lane & 15, kb = (lane >> 4) * 8;
#pragma unroll
    for (int mi = 0; mi < 2; ++mi) {
      float v[8];
#pragma unroll
      for (int j = 0; j < 8; ++j)
        v[j] = (o < 10) ? W3[o * 64 + kb + 32 * mi + j] : 0.f;
      unsigned t[4];
      t[0] = packbf2(v[0], v[1]); t[1] = packbf2(v[2], v[3]);
      t[2] = packbf2(v[4], v[5]); t[3] = packbf2(v[6], v[7]);
      w3f[mi] = __builtin_bit_cast(bf16x8, *(unsigned(*)[4])t);
    }
  }
  const float b12v = smemF[BOFF / 4 + (lane & 15)];
  float b3v[4];
#pragma unroll
  for (int r = 0; r < 4; ++r) {
    int o = (lane >> 4) * 4 + r;
    b3v[r] = (o < 10) ? b3[o] : 0.f;
  }
  // All waves have W12 in registers; y-region may now alias it.
  __syncthreads();

  // ---- per-wave zero of x-stage K-pad (bytes [392,464) of each row) ------
  char* xw = smem + waveid * 7424;
#pragma unroll
  for (int j = 0; j < 5; ++j) {
    int idx = lane + 64 * j;
    if (idx < 288) {
      int row = idx / 18, d = idx - row * 18;
      *(unsigned*)(xw + row * XS + 392 + d * 4) = 0;
    }
  }

  // ---- staging addresses: raster float4 -> quadrant-stream bf16 pairs ----
  unsigned wa0[13]; unsigned strm = 0;
#pragma unroll
  for (int it = 0; it < 13; ++it) {
    int gi = lane + 64 * it;
    int im = gi / 196, rem = gi - im * 196;      // image, float4 within image
    int rr = rem / 7, t = rem - rr * 7;          // pixel row, 4-px group
    int c2 = 2 * t;                              // first bf16-pair column
    int J = c2 / 7, cq = c2 - 7 * J;
    int row = im * 4 + (rr / 14) * 2 + J;        // M-row = im*4 + (I*2+J)
    int kp = (rr % 14) * 7 + cq;                 // pair index in quadrant
    wa0[it] = waveid * 7424 + row * XS + kp * 4;
    if (t == 3) strm |= (1u << it);              // second pair crosses J-half
  }

  const unsigned xrd = waveid * 7424 + (lane & 15) * XS + (lane >> 4) * 16;
  const unsigned ywb = YOFF + waveid * 2304 + (lane & 15) * 2;
  const unsigned yrd = YOFF + waveid * 2304 + (lane & 15) * YS + (lane >> 4) * 16;

  const int NU = nimg >> 4;                      // 16-image units
  const int WST = (int)(gridDim.x << 2);         // total waves
  const int w0 = (int)(blockIdx.x << 2) + waveid;
  const int ng4 = nimg >> 2;                     // 4-image groups

  f32x4 cur[13];
  const f32x4* __restrict__ xq0 = (const f32x4*)x;
  auto issue4 = [&](int g4) {                    // 13 coalesced NT dwordx4 loads
    const f32x4* p = xq0 + (size_t)g4 * 784;
#pragma unroll
    for (int it = 0; it < 12; ++it)
      cur[it] = __builtin_nontemporal_load(p + lane + 64 * it);
    if (lane < 16) cur[12] = __builtin_nontemporal_load(p + 768 + lane);
  };

  if (w0 < NU) issue4(w0 * 4);

  for (int u = w0; u < NU; u += WST) {
#pragma unroll 1
    for (int sb = 0; sb < 4; ++sb) {
      // stage cur -> LDS (compiler inserts the vmcnt wait on cur)
#pragma unroll
      for (int it = 0; it < 13; ++it) {
        if (it == 12 && lane >= 16) continue;
        f32x4 v = cur[it];
        unsigned a0 = wa0[it];
        unsigned d = ((strm >> it) & 1) ? 440u : 4u;
        *(unsigned*)(smem + a0) = packbf2(v.x, v.y);
        *(unsigned*)(smem + a0 + d) = packbf2(v.z, v.w);
      }
      // prefetch next 4-image group (1 sub-batch deep)
      int ng = (sb < 3) ? (u * 4 + sb + 1) : ((u + WST) * 4);
      if (ng < ng4) issue4(ng);
      // GEMM1: y(16 rows x 16 f2) = P(16 x 224) * W12(224 x 16)
      f32x4 acc = {0.f, 0.f, 0.f, 0.f};
#pragma unroll
      for (int i = 0; i < 7; ++i) {
        bf16x8 a = *(const bf16x8*)(smem + xrd + 64 * i);
        acc = __builtin_amdgcn_mfma_f32_16x16x32_bf16(a, wfrag[i], acc, 0, 0, 0);
      }
      // bias + ReLU + bf16 -> y LDS  (D: img=lane>>4, q=r, f2=lane&15)
      unsigned yb = ywb + (unsigned)(sb * 4 + (lane >> 4)) * YS;
#pragma unroll
      for (int r = 0; r < 4; ++r) {
        float yv = fmaxf(acc[r] + b12v, 0.f);
        *(unsigned short*)(smem + yb + r * 32) = f2bf(yv);
      }
    }
    // GEMM2: z^T(16 o x 16 img) = W3(16x64) * y^T(64x16) over the unit
    f32x4 z4 = {0.f, 0.f, 0.f, 0.f};
#pragma unroll
    for (int mi = 0; mi < 2; ++mi) {
      bf16x8 bfr = *(const bf16x8*)(smem + yrd + 64 * mi);
      z4 = __builtin_amdgcn_mfma_f32_16x16x32_bf16(w3f[mi], bfr, z4, 0, 0, 0);
    }
    // log_softmax over o = (lane>>4)*4 + r (10 valid), img = lane&15
    float zv[4], mval = -3.0e38f;
#pragma unroll
    for (int r = 0; r < 4; ++r) {
      zv[r] = z4[r] + b3v[r];
      bool valid = ((lane >> 4) * 4 + r) < 10;
      mval = fmaxf(mval, valid ? zv[r] : -3.0e38f);
    }
    mval = fmaxf(mval, __shfl_xor(mval, 16, 64));
    mval = fmaxf(mval, __shfl_xor(mval, 32, 64));
    float ssum = 0.f;
#pragma unroll
    for (int r = 0; r < 4; ++r) {
      bool valid = ((lane >> 4) * 4 + r) < 10;
      ssum += valid ? __expf(zv[r] - mval) : 0.f;
    }
    ssum += __shfl_xor(ssum, 16, 64);
    ssum += __shfl_xor(ssum, 32, 64);
    const float lse = mval + __logf(ssum);
    float* op = out + (size_t)(u * 16 + (lane & 15)) * 10;
#pragma unroll
    for (int r = 0; r < 4; ++r) {
      int o = (lane >> 4) * 4 + r;
      if (o < 10) op[o] = zv[r] - lse;
    }
  }
}

extern "C" void kernel_launch(void* const* d_in, const int* in_sizes, int n_in,
                              void* d_out, int out_size, void* d_ws, size_t ws_size,
                              hipStream_t stream) {
  const float* x  = (const float*)d_in[0];
  const float* W1 = (const float*)d_in[1];
  const float* b1 = (const float*)d_in[2];
  const float* W2 = (const float*)d_in[3];
  const float* b2 = (const float*)d_in[4];
  const float* W3 = (const float*)d_in[5];
  const float* b3 = (const float*)d_in[6];
  float* out = (float*)d_out;

  const int nimg = in_sizes[0] / 784;  // 131072
  // 1024 blocks = 4096 waves -> exactly 2 units/wave; 4 blocks/CU at 39 KB LDS.
  mnist_mfma<<<1024, 256, 0, stream>>>(x, W1, b1, W2, b2, W3, b3, out, nimg);
}